// Round 1
// baseline (1110.372 us; speedup 1.0000x reference)
//
#include <hip/hip_runtime.h>
#include <hip/hip_bf16.h>

#define BB 8
#define NN 16384
#define CC 128
#define NH 8
#define HD 16

// ---------------------------------------------------------------------------
// Kernel A: q/k projection + focusing transform + per-block reduction partials
// grid 4096 (32 tokens/block), block 256
// ---------------------------------------------------------------------------
__global__ __launch_bounds__(256) void qk_kernel(
    const float* __restrict__ x, const float* __restrict__ Wq,
    const float* __restrict__ Wkv, const float* __restrict__ w_g,
    const float* __restrict__ scale, const float* __restrict__ pos_enc,
    float* __restrict__ qout, float* __restrict__ kout,
    float* __restrict__ partial)
{
    __shared__ float xs[32 * 128];
    __shared__ float qs[32 * 128];
    __shared__ float ks_[32 * 128];
    __shared__ float fq[32], fk[32], apre[32];

    const int tid  = threadIdx.x;
    const int blk  = blockIdx.x;
    const int tile = blk & 511;            // tile within batch (N/32 = 512)
    const int base = blk * (32 * 128);     // flat float offset of this token tile

    // load x tile
    for (int idx = tid; idx < 32 * 128; idx += 256)
        xs[idx] = x[base + idx];
    __syncthreads();

    const int c    = tid & 127;
    const int half = tid >> 7;

    float accq[16], acck[16];
#pragma unroll
    for (int j = 0; j < 16; ++j) { accq[j] = 0.f; acck[j] = 0.f; }

    const float* wqr = Wq  + c * 128;
    const float* wkr = Wkv + c * 128;
    for (int i = 0; i < 128; i += 4) {
        const float4 wq4 = *(const float4*)(wqr + i);
        const float4 wk4 = *(const float4*)(wkr + i);
#pragma unroll
        for (int j = 0; j < 16; ++j) {
            const float4 xv = *(const float4*)(&xs[(half + 2 * j) * 128 + i]);
            accq[j] += xv.x * wq4.x + xv.y * wq4.y + xv.z * wq4.z + xv.w * wq4.w;
            acck[j] += xv.x * wk4.x + xv.y * wk4.y + xv.z * wk4.z + xv.w * wk4.w;
        }
    }

    // activation: s = softplus(scale); q=(relu+1e-6)/s ; k gets pos_enc first
    const float s     = log1pf(expf(scale[c]));
    const float inv_s = 1.f / s;
#pragma unroll
    for (int j = 0; j < 16; ++j) {
        const int tt = half + 2 * j;
        const int m  = tile * 32 + tt;     // token index within batch
        float qv = (fmaxf(accq[j], 0.f) + 1e-6f) * inv_s;
        float kv = (fmaxf(acck[j] + pos_enc[m * 128 + c], 0.f) + 1e-6f) * inv_s;
        qs[tt * 128 + c] = qv;
        ks_[tt * 128 + c] = kv;
    }
    __syncthreads();

    // per-token norms: ||q||, ||q^3||, ||k||, ||k^3||
    const int wid  = tid >> 6;
    const int lane = tid & 63;
    for (int t = wid; t < 32; t += 4) {
        float q0 = qs[t * 128 + lane],      q1 = qs[t * 128 + 64 + lane];
        float k0 = ks_[t * 128 + lane],     k1 = ks_[t * 128 + 64 + lane];
        float q0_2 = q0 * q0, q1_2 = q1 * q1, k0_2 = k0 * k0, k1_2 = k1 * k1;
        float sq2 = q0_2 + q1_2;
        float sk2 = k0_2 + k1_2;
        float sq6 = q0_2 * q0_2 * q0_2 + q1_2 * q1_2 * q1_2;
        float sk6 = k0_2 * k0_2 * k0_2 + k1_2 * k1_2 * k1_2;
#pragma unroll
        for (int o = 32; o >= 1; o >>= 1) {
            sq2 += __shfl_xor(sq2, o);
            sq6 += __shfl_xor(sq6, o);
            sk2 += __shfl_xor(sk2, o);
            sk6 += __shfl_xor(sk6, o);
        }
        if (lane == 0) {
            fq[t] = sqrtf(sq2 / sq6);   // ||q|| / ||q^3||
            fk[t] = sqrtf(sk2 / sk6);
        }
    }
    __syncthreads();

    // finalize focused q,k ; write out and keep in LDS
    for (int idx = tid; idx < 4096; idx += 256) {
        const int t = idx >> 7;
        float qv = qs[idx];
        float kv = ks_[idx];
        float qf = qv * qv * qv * fq[t];
        float kf = kv * kv * kv * fk[t];
        qs[idx] = qf;
        ks_[idx] = kf;
        qout[base + idx] = qf;
        kout[base + idx] = kf;
    }
    __syncthreads();

    // A_pre per token: dot(q, w_g) * 0.25
    {
        const float wg0 = w_g[lane], wg1 = w_g[64 + lane];
        for (int t = wid; t < 32; t += 4) {
            float a = qs[t * 128 + lane] * wg0 + qs[t * 128 + 64 + lane] * wg1;
#pragma unroll
            for (int o = 32; o >= 1; o >>= 1) a += __shfl_xor(a, o);
            if (lane == 0) apre[t] = a * 0.25f;
        }
    }
    __syncthreads();

    // per-block partials: Gpartial[128], ksum[128], sumsqA[1]
    float* pblk = partial + blk * 257;
    if (tid < 128) {
        float g = 0.f, ksum = 0.f;
        for (int t = 0; t < 32; ++t) {
            g    += apre[t] * qs[t * 128 + tid];
            ksum += ks_[t * 128 + tid];
        }
        pblk[tid] = g;
        pblk[128 + tid] = ksum;
    }
    if (tid == 255) {
        float ssa = 0.f;
        for (int t = 0; t < 32; ++t) ssa += apre[t] * apre[t];
        pblk[256] = ssa;
    }
}

// ---------------------------------------------------------------------------
// Kernel B: reduce partials -> G (B,C), kbar (B,C). grid 8, block 256
// ---------------------------------------------------------------------------
__global__ __launch_bounds__(256) void reduce_kernel(
    const float* __restrict__ partial, float* __restrict__ G,
    float* __restrict__ kbar)
{
    const int b = blockIdx.x;
    const int tid = threadIdx.x;
    __shared__ float tmp[4];

    float ssa = 0.f;
    for (int t = tid; t < 512; t += 256)
        ssa += partial[(b * 512 + t) * 257 + 256];
#pragma unroll
    for (int o = 32; o >= 1; o >>= 1) ssa += __shfl_xor(ssa, o);
    if ((tid & 63) == 0) tmp[tid >> 6] = ssa;
    __syncthreads();
    const float anorm = fmaxf(sqrtf(tmp[0] + tmp[1] + tmp[2] + tmp[3]), 1e-12f);
    const float inv_a = 1.f / anorm;

    if (tid < 128) {
        float g = 0.f;
        for (int t = 0; t < 512; ++t)
            g += partial[(b * 512 + t) * 257 + tid];
        G[b * 128 + tid] = g * inv_a;
    } else {
        const int c2 = tid - 128;
        float s = 0.f;
        for (int t = 0; t < 512; ++t)
            s += partial[(b * 512 + t) * 257 + 128 + c2];
        kbar[b * 128 + c2] = s * (1.f / 16384.f);
    }
}

// ---------------------------------------------------------------------------
// Kernel C: z + gating + cube-transpose scramble + inline depthwise 5x5 conv
// grid 1024 = (b, r), block 256. Writes scrambled rows n = cc*128 + r of d_out
// ---------------------------------------------------------------------------
__global__ __launch_bounds__(256) void zconv_kernel(
    const float* __restrict__ q, const float* __restrict__ k,
    const float* __restrict__ G, const float* __restrict__ kbar,
    const float* __restrict__ dwc_w, const float* __restrict__ dwc_b,
    float* __restrict__ out)
{
    __shared__ float u[128 * 129];
    __shared__ float Gl[128], kbl[128], wc[16 * 25], bi[16];

    const int tid = threadIdx.x;
    const int b = blockIdx.x >> 7;
    const int r = blockIdx.x & 127;

    if (tid < 128) { Gl[tid] = G[b * 128 + tid]; kbl[tid] = kbar[b * 128 + tid]; }
    for (int i = tid; i < 400; i += 256) wc[i] = dwc_w[i];
    if (tid < 16) bi[tid] = dwc_b[tid];
    __syncthreads();

    const int wid  = tid >> 6;
    const int lane = tid & 63;
    const int kbase = (b * NN + r * 128) * CC;

    for (int mm = wid; mm < 128; mm += 4) {
        const int off = kbase + mm * 128;
        const float k0 = k[off + lane],      k1 = k[off + 64 + lane];
        const float q0 = q[off + lane],      q1 = q[off + 64 + lane];
        float p0 = q0 * kbl[lane];
        float p1 = q1 * kbl[64 + lane];
#pragma unroll
        for (int o = 1; o < 16; o <<= 1) {
            p0 += __shfl_xor(p0, o);
            p1 += __shfl_xor(p1, o);
        }
        const float z0 = 1.f / (p0 + 1e-6f);
        const float z1 = 1.f / (p1 + 1e-6f);
        u[mm * 129 + lane]      = Gl[lane] * k0 * z0;
        u[mm * 129 + 64 + lane] = Gl[64 + lane] * k1 * z1;
    }
    __syncthreads();

    for (int idx = tid; idx < 16384; idx += 256) {
        const int cc = idx >> 7;   // output row group = spatial y of conv
        const int ch = idx & 127;
        const int d = ch & 15;
        float acc = bi[d];
#pragma unroll
        for (int dy = 0; dy < 5; ++dy) {
            const int yy = cc + dy - 2;
            if (yy < 0 || yy > 127) continue;
#pragma unroll
            for (int dx = 0; dx < 5; ++dx) {
                const int xx = r + dx - 2;
                if (xx < 0 || xx > 127) continue;
                acc += wc[d * 25 + dy * 5 + dx] *
                       k[(b * NN + yy * 128 + xx) * CC + ch];
            }
        }
        const float val = u[ch * 129 + cc] + acc;
        out[(b * NN + cc * 128 + r) * CC + ch] = val;
    }
}

// ---------------------------------------------------------------------------
// Kernel D: in-place projection  out = out @ Wproj.T + bproj
// grid 4096 (32 rows/block), block 256
// ---------------------------------------------------------------------------
__global__ __launch_bounds__(256) void proj_kernel(
    float* __restrict__ out, const float* __restrict__ Wp,
    const float* __restrict__ bp)
{
    __shared__ float xs[32 * 128];
    const int tid = threadIdx.x;
    const int base = blockIdx.x * (32 * 128);

    for (int idx = tid; idx < 4096; idx += 256)
        xs[idx] = out[base + idx];
    __syncthreads();

    const int c    = tid & 127;
    const int half = tid >> 7;
    const float* wr = Wp + c * 128;

    float acc[16];
#pragma unroll
    for (int j = 0; j < 16; ++j) acc[j] = 0.f;

    for (int i = 0; i < 128; i += 4) {
        const float4 w4 = *(const float4*)(wr + i);
#pragma unroll
        for (int j = 0; j < 16; ++j) {
            const float4 xv = *(const float4*)(&xs[(half + 2 * j) * 128 + i]);
            acc[j] += xv.x * w4.x + xv.y * w4.y + xv.z * w4.z + xv.w * w4.w;
        }
    }
    const float bias = bp[c];
#pragma unroll
    for (int j = 0; j < 16; ++j)
        out[base + (half + 2 * j) * 128 + c] = acc[j] + bias;
}

// ---------------------------------------------------------------------------
extern "C" void kernel_launch(void* const* d_in, const int* in_sizes, int n_in,
                              void* d_out, int out_size, void* d_ws, size_t ws_size,
                              hipStream_t stream)
{
    const float* x       = (const float*)d_in[0];
    const float* Wq      = (const float*)d_in[1];
    const float* Wkv     = (const float*)d_in[2];
    const float* Wproj   = (const float*)d_in[3];
    const float* bproj   = (const float*)d_in[4];
    const float* w_g     = (const float*)d_in[5];
    const float* scale   = (const float*)d_in[6];
    const float* pos_enc = (const float*)d_in[7];
    const float* dwc_w   = (const float*)d_in[8];
    const float* dwc_b   = (const float*)d_in[9];
    float* out = (float*)d_out;

    char* ws = (char*)d_ws;
    float* qbuf    = (float*)(ws);                       // 67108864 B
    float* kbuf    = (float*)(ws + 67108864);            // 67108864 B
    float* partial = (float*)(ws + 134217728);           // 4096*257*4 = 4210688 B
    float* G       = (float*)(ws + 138428416);           // 4096 B
    float* kbar    = (float*)(ws + 138432512);           // 4096 B

    qk_kernel<<<dim3(4096), dim3(256), 0, stream>>>(
        x, Wq, Wkv, w_g, scale, pos_enc, qbuf, kbuf, partial);
    reduce_kernel<<<dim3(8), dim3(256), 0, stream>>>(partial, G, kbar);
    zconv_kernel<<<dim3(1024), dim3(256), 0, stream>>>(
        qbuf, kbuf, G, kbar, dwc_w, dwc_b, out);
    proj_kernel<<<dim3(4096), dim3(256), 0, stream>>>(out, Wproj, bproj);
}

// Round 2
// 536.704 us; speedup vs baseline: 2.0689x; 2.0689x over previous
//
#include <hip/hip_runtime.h>
#include <hip/hip_bf16.h>

#define BB 8
#define NN 16384
#define CC 128
#define NH 8
#define HD 16

// ---------------------------------------------------------------------------
// Kernel A: q/k projection + focusing transform + per-block reduction partials
// grid 4096 (32 tokens/block), block 256
// ---------------------------------------------------------------------------
__global__ __launch_bounds__(256) void qk_kernel(
    const float* __restrict__ x, const float* __restrict__ Wq,
    const float* __restrict__ Wkv, const float* __restrict__ w_g,
    const float* __restrict__ scale, const float* __restrict__ pos_enc,
    float* __restrict__ qout, float* __restrict__ kout,
    float* __restrict__ partial)
{
    __shared__ float xs[32 * 128];
    __shared__ float qs[32 * 128];
    __shared__ float ks_[32 * 128];
    __shared__ float fq[32], fk[32], apre[32];

    const int tid  = threadIdx.x;
    const int blk  = blockIdx.x;
    const int tile = blk & 511;            // tile within batch (N/32 = 512)
    const int base = blk * (32 * 128);     // flat float offset of this token tile

    // load x tile
    for (int idx = tid; idx < 32 * 128; idx += 256)
        xs[idx] = x[base + idx];
    __syncthreads();

    const int c    = tid & 127;
    const int half = tid >> 7;

    float accq[16], acck[16];
#pragma unroll
    for (int j = 0; j < 16; ++j) { accq[j] = 0.f; acck[j] = 0.f; }

    const float* wqr = Wq  + c * 128;
    const float* wkr = Wkv + c * 128;
    for (int i = 0; i < 128; i += 4) {
        const float4 wq4 = *(const float4*)(wqr + i);
        const float4 wk4 = *(const float4*)(wkr + i);
#pragma unroll
        for (int j = 0; j < 16; ++j) {
            const float4 xv = *(const float4*)(&xs[(half + 2 * j) * 128 + i]);
            accq[j] += xv.x * wq4.x + xv.y * wq4.y + xv.z * wq4.z + xv.w * wq4.w;
            acck[j] += xv.x * wk4.x + xv.y * wk4.y + xv.z * wk4.z + xv.w * wk4.w;
        }
    }

    // activation: s = softplus(scale); q=(relu+1e-6)/s ; k gets pos_enc first
    const float s     = log1pf(expf(scale[c]));
    const float inv_s = 1.f / s;
#pragma unroll
    for (int j = 0; j < 16; ++j) {
        const int tt = half + 2 * j;
        const int m  = tile * 32 + tt;     // token index within batch
        float qv = (fmaxf(accq[j], 0.f) + 1e-6f) * inv_s;
        float kv = (fmaxf(acck[j] + pos_enc[m * 128 + c], 0.f) + 1e-6f) * inv_s;
        qs[tt * 128 + c] = qv;
        ks_[tt * 128 + c] = kv;
    }
    __syncthreads();

    // per-token norms: ||q||, ||q^3||, ||k||, ||k^3||
    const int wid  = tid >> 6;
    const int lane = tid & 63;
    for (int t = wid; t < 32; t += 4) {
        float q0 = qs[t * 128 + lane],      q1 = qs[t * 128 + 64 + lane];
        float k0 = ks_[t * 128 + lane],     k1 = ks_[t * 128 + 64 + lane];
        float q0_2 = q0 * q0, q1_2 = q1 * q1, k0_2 = k0 * k0, k1_2 = k1 * k1;
        float sq2 = q0_2 + q1_2;
        float sk2 = k0_2 + k1_2;
        float sq6 = q0_2 * q0_2 * q0_2 + q1_2 * q1_2 * q1_2;
        float sk6 = k0_2 * k0_2 * k0_2 + k1_2 * k1_2 * k1_2;
#pragma unroll
        for (int o = 32; o >= 1; o >>= 1) {
            sq2 += __shfl_xor(sq2, o);
            sq6 += __shfl_xor(sq6, o);
            sk2 += __shfl_xor(sk2, o);
            sk6 += __shfl_xor(sk6, o);
        }
        if (lane == 0) {
            fq[t] = sqrtf(sq2 / sq6);   // ||q|| / ||q^3||
            fk[t] = sqrtf(sk2 / sk6);
        }
    }
    __syncthreads();

    // finalize focused q,k ; write out and keep in LDS
    for (int idx = tid; idx < 4096; idx += 256) {
        const int t = idx >> 7;
        float qv = qs[idx];
        float kv = ks_[idx];
        float qf = qv * qv * qv * fq[t];
        float kf = kv * kv * kv * fk[t];
        qs[idx] = qf;
        ks_[idx] = kf;
        qout[base + idx] = qf;
        kout[base + idx] = kf;
    }
    __syncthreads();

    // A_pre per token: dot(q, w_g) * 0.25
    {
        const float wg0 = w_g[lane], wg1 = w_g[64 + lane];
        for (int t = wid; t < 32; t += 4) {
            float a = qs[t * 128 + lane] * wg0 + qs[t * 128 + 64 + lane] * wg1;
#pragma unroll
            for (int o = 32; o >= 1; o >>= 1) a += __shfl_xor(a, o);
            if (lane == 0) apre[t] = a * 0.25f;
        }
    }
    __syncthreads();

    // per-block partials: Gpartial[128], ksum[128], sumsqA[1]
    float* pblk = partial + blk * 257;
    if (tid < 128) {
        float g = 0.f, ksum = 0.f;
        for (int t = 0; t < 32; ++t) {
            g    += apre[t] * qs[t * 128 + tid];
            ksum += ks_[t * 128 + tid];
        }
        pblk[tid] = g;
        pblk[128 + tid] = ksum;
    }
    if (tid == 255) {
        float ssa = 0.f;
        for (int t = 0; t < 32; ++t) ssa += apre[t] * apre[t];
        pblk[256] = ssa;
    }
}

// ---------------------------------------------------------------------------
// Kernel B: reduce partials -> G (B,C), kbar (B,C). grid 8, block 256
// ---------------------------------------------------------------------------
__global__ __launch_bounds__(256) void reduce_kernel(
    const float* __restrict__ partial, float* __restrict__ G,
    float* __restrict__ kbar)
{
    const int b = blockIdx.x;
    const int tid = threadIdx.x;
    __shared__ float tmp[4];

    float ssa = 0.f;
    for (int t = tid; t < 512; t += 256)
        ssa += partial[(b * 512 + t) * 257 + 256];
#pragma unroll
    for (int o = 32; o >= 1; o >>= 1) ssa += __shfl_xor(ssa, o);
    if ((tid & 63) == 0) tmp[tid >> 6] = ssa;
    __syncthreads();
    const float anorm = fmaxf(sqrtf(tmp[0] + tmp[1] + tmp[2] + tmp[3]), 1e-12f);
    const float inv_a = 1.f / anorm;

    if (tid < 128) {
        float g = 0.f;
        for (int t = 0; t < 512; ++t)
            g += partial[(b * 512 + t) * 257 + tid];
        G[b * 128 + tid] = g * inv_a;
    } else {
        const int c2 = tid - 128;
        float s = 0.f;
        for (int t = 0; t < 512; ++t)
            s += partial[(b * 512 + t) * 257 + 128 + c2];
        kbar[b * 128 + c2] = s * (1.f / 16384.f);
    }
}

// ---------------------------------------------------------------------------
// Kernel C1: z + gating + cube-transpose scramble (no conv)
// grid 2048 = (b, r, half), block 256. LDS 33 KB -> 4 blocks/CU.
// out[(cc*128 + r)*128 + half*64 + ch] = u[token=ch][channel=cc]
// ---------------------------------------------------------------------------
__global__ __launch_bounds__(256) void scramble_kernel(
    const float* __restrict__ q, const float* __restrict__ k,
    const float* __restrict__ G, const float* __restrict__ kbar,
    float* __restrict__ out)
{
    __shared__ float u[64 * 129];
    const int tid  = threadIdx.x;
    const int bid  = blockIdx.x;
    const int half = bid & 1;
    const int r    = (bid >> 1) & 127;
    const int b    = bid >> 8;

    const int t  = tid >> 2;      // token-in-block 0..63
    const int qt = tid & 3;       // channel quarter 0..3
    const int tok   = r * 128 + half * 64 + t;
    const int gbase = (b * NN + tok) * CC + qt * 32;
    const int cb    = b * CC + qt * 32;

    float4 qv[8], kv[8], kb4[8], g4[8];
#pragma unroll
    for (int j = 0; j < 8; ++j) {
        qv[j]  = *(const float4*)(q + gbase + j * 4);
        kv[j]  = *(const float4*)(k + gbase + j * 4);
        kb4[j] = *(const float4*)(kbar + cb + j * 4);
        g4[j]  = *(const float4*)(G + cb + j * 4);
    }
    // per-head dots: head A = ch [qt*32, qt*32+16), head B = next 16
    float dot0 = 0.f, dot1 = 0.f;
#pragma unroll
    for (int j = 0; j < 4; ++j) {
        dot0 += qv[j].x * kb4[j].x + qv[j].y * kb4[j].y +
                qv[j].z * kb4[j].z + qv[j].w * kb4[j].w;
        dot1 += qv[j + 4].x * kb4[j + 4].x + qv[j + 4].y * kb4[j + 4].y +
                qv[j + 4].z * kb4[j + 4].z + qv[j + 4].w * kb4[j + 4].w;
    }
    const float z0 = 1.f / (dot0 + 1e-6f);
    const float z1 = 1.f / (dot1 + 1e-6f);

    float* ut = u + t * 129 + qt * 32;
#pragma unroll
    for (int j = 0; j < 8; ++j) {
        const float zz = (j < 4) ? z0 : z1;
        ut[j * 4 + 0] = g4[j].x * kv[j].x * zz;
        ut[j * 4 + 1] = g4[j].y * kv[j].y * zz;
        ut[j * 4 + 2] = g4[j].z * kv[j].z * zz;
        ut[j * 4 + 3] = g4[j].w * kv[j].w * zz;
    }
    __syncthreads();

    // transpose write: 8192 outputs, coalesced 256B over ch
    const int obase = b * NN * CC + half * 64;
#pragma unroll
    for (int it = 0; it < 32; ++it) {
        const int idx = tid + it * 256;
        const int cc  = idx >> 6;       // output channel (= u col)
        const int ch  = idx & 63;       // token-in-block (= u row)
        out[obase + (cc * 128 + r) * CC + ch] = u[ch * 129 + cc];
    }
}

// ---------------------------------------------------------------------------
// Kernel C2: depthwise 5x5 conv, RMW into out (un-scrambled coordinates)
// out[b, y*128+x, ch] += conv(y,x,ch) + bias
// thread = (x, 2 channels); block = 4 x * 64 ch2; grid b8 * xg32 * ystrip16
// ---------------------------------------------------------------------------
__global__ __launch_bounds__(256) void conv_kernel(
    const float* __restrict__ k, const float* __restrict__ dwc_w,
    const float* __restrict__ dwc_b, float* __restrict__ out)
{
    const int tid = threadIdx.x;
    const int l   = tid & 63;         // ch2 lane (channels 2l, 2l+1)
    const int xl  = tid >> 6;         // 0..3
    const int bid = blockIdx.x;
    const int ystrip = bid & 15;
    const int xg  = (bid >> 4) & 31;
    const int b   = bid >> 9;
    const int x   = xg * 4 + xl;
    const int y0  = ystrip * 8;

    const int d0 = (2 * l) & 15;
    const int d1 = (2 * l + 1) & 15;

    float2 w2[25];
#pragma unroll
    for (int j = 0; j < 25; ++j) {
        w2[j].x = dwc_w[d0 * 25 + j];
        w2[j].y = dwc_w[d1 * 25 + j];
    }
    const float bx = dwc_b[d0], by = dwc_b[d1];

    float2 acc[8];
#pragma unroll
    for (int i = 0; i < 8; ++i) acc[i] = make_float2(0.f, 0.f);

    const float2* k2 = (const float2*)k;
    const int base = b * (NN * 64);

    bool mx[5];
#pragma unroll
    for (int dx = 0; dx < 5; ++dx) {
        const int xx = x + dx - 2;
        mx[dx] = (xx >= 0 && xx < 128);
    }

#pragma unroll
    for (int i = 0; i < 12; ++i) {
        const int yy = y0 + i - 2;
        const bool vy = (yy >= 0 && yy < 128);
        float2 c[5];
#pragma unroll
        for (int dx = 0; dx < 5; ++dx) {
            const int xx = x + dx - 2;
            c[dx] = (vy && mx[dx]) ? k2[base + (yy * 128 + xx) * 64 + l]
                                   : make_float2(0.f, 0.f);
        }
#pragma unroll
        for (int dy = 0; dy < 5; ++dy) {
            const int oy = i - dy;          // output index in strip
            if (oy < 0 || oy >= 8) continue; // compile-time after unroll
#pragma unroll
            for (int dx = 0; dx < 5; ++dx) {
                acc[oy].x += w2[dy * 5 + dx].x * c[dx].x;
                acc[oy].y += w2[dy * 5 + dx].y * c[dx].y;
            }
        }
    }

    float2* o2 = (float2*)out;
#pragma unroll
    for (int i = 0; i < 8; ++i) {
        const int idx = base + ((y0 + i) * 128 + x) * 64 + l;
        float2 v = o2[idx];
        v.x += acc[i].x + bx;
        v.y += acc[i].y + by;
        o2[idx] = v;
    }
}

// ---------------------------------------------------------------------------
// Kernel D: in-place projection  out = out @ Wproj.T + bproj
// grid 4096 (32 rows/block), block 256
// ---------------------------------------------------------------------------
__global__ __launch_bounds__(256) void proj_kernel(
    float* __restrict__ out, const float* __restrict__ Wp,
    const float* __restrict__ bp)
{
    __shared__ float xs[32 * 128];
    const int tid = threadIdx.x;
    const int base = blockIdx.x * (32 * 128);

    for (int idx = tid; idx < 4096; idx += 256)
        xs[idx] = out[base + idx];
    __syncthreads();

    const int c    = tid & 127;
    const int half = tid >> 7;
    const float* wr = Wp + c * 128;

    float acc[16];
#pragma unroll
    for (int j = 0; j < 16; ++j) acc[j] = 0.f;

    for (int i = 0; i < 128; i += 4) {
        const float4 w4 = *(const float4*)(wr + i);
#pragma unroll
        for (int j = 0; j < 16; ++j) {
            const float4 xv = *(const float4*)(&xs[(half + 2 * j) * 128 + i]);
            acc[j] += xv.x * w4.x + xv.y * w4.y + xv.z * w4.z + xv.w * w4.w;
        }
    }
    const float bias = bp[c];
#pragma unroll
    for (int j = 0; j < 16; ++j)
        out[base + (half + 2 * j) * 128 + c] = acc[j] + bias;
}

// ---------------------------------------------------------------------------
extern "C" void kernel_launch(void* const* d_in, const int* in_sizes, int n_in,
                              void* d_out, int out_size, void* d_ws, size_t ws_size,
                              hipStream_t stream)
{
    const float* x       = (const float*)d_in[0];
    const float* Wq      = (const float*)d_in[1];
    const float* Wkv     = (const float*)d_in[2];
    const float* Wproj   = (const float*)d_in[3];
    const float* bproj   = (const float*)d_in[4];
    const float* w_g     = (const float*)d_in[5];
    const float* scale   = (const float*)d_in[6];
    const float* pos_enc = (const float*)d_in[7];
    const float* dwc_w   = (const float*)d_in[8];
    const float* dwc_b   = (const float*)d_in[9];
    float* out = (float*)d_out;

    char* ws = (char*)d_ws;
    float* qbuf    = (float*)(ws);                       // 67108864 B
    float* kbuf    = (float*)(ws + 67108864);            // 67108864 B
    float* partial = (float*)(ws + 134217728);           // 4096*257*4 = 4210688 B
    float* G       = (float*)(ws + 138428416);           // 4096 B
    float* kbar    = (float*)(ws + 138432512);           // 4096 B

    qk_kernel<<<dim3(4096), dim3(256), 0, stream>>>(
        x, Wq, Wkv, w_g, scale, pos_enc, qbuf, kbuf, partial);
    reduce_kernel<<<dim3(8), dim3(256), 0, stream>>>(partial, G, kbar);
    scramble_kernel<<<dim3(2048), dim3(256), 0, stream>>>(
        qbuf, kbuf, G, kbar, out);
    conv_kernel<<<dim3(4096), dim3(256), 0, stream>>>(
        kbuf, dwc_w, dwc_b, out);
    proj_kernel<<<dim3(4096), dim3(256), 0, stream>>>(out, Wproj, bproj);
}

// Round 3
// 298.198 us; speedup vs baseline: 3.7236x; 1.7998x over previous
//
#include <hip/hip_runtime.h>
#include <hip/hip_bf16.h>

#define BB 8
#define NN 16384
#define CC 128
#define NH 8
#define HD 16

typedef __attribute__((ext_vector_type(8))) short bf16x8;
typedef __attribute__((ext_vector_type(4))) short short4v;
typedef __attribute__((ext_vector_type(4))) float f32x4;

__device__ __forceinline__ unsigned short f2bf(float f) {
    union { float f; unsigned u; } v; v.f = f;
    unsigned r = v.u + 0x7fffu + ((v.u >> 16) & 1u);
    return (unsigned short)(r >> 16);
}
__device__ __forceinline__ float bf2f(unsigned short h) {
    union { unsigned u; float f; } v; v.u = ((unsigned)h) << 16;
    return v.f;
}

// ---------------------------------------------------------------------------
// W prep: split Wq, Wkv, Wproj into bf16 hi/lo. grid 48, block 256.
// ---------------------------------------------------------------------------
__global__ __launch_bounds__(256) void wprep_kernel(
    const float* __restrict__ Wq, const float* __restrict__ Wkv,
    const float* __restrict__ Wp,
    unsigned short* __restrict__ whi, unsigned short* __restrict__ wlo)
{
    const int bid = blockIdx.x;
    const int mat = bid >> 4;
    const float* src = (mat == 0) ? Wq : ((mat == 1) ? Wkv : Wp);
    const int off = (bid & 15) * 1024 + threadIdx.x * 4;
    const float4 v = *(const float4*)(src + off);
    float f[4] = {v.x, v.y, v.z, v.w};
    short4v hv, lv;
#pragma unroll
    for (int j = 0; j < 4; ++j) {
        unsigned short h = f2bf(f[j]);
        hv[j] = (short)h;
        lv[j] = (short)f2bf(f[j] - bf2f(h));
    }
    *(short4v*)(whi + mat * 16384 + off) = hv;
    *(short4v*)(wlo + mat * 16384 + off) = lv;
}

// ---------------------------------------------------------------------------
// qk MFMA kernel: q/k projection (split-bf16 MFMA) + focusing + partials.
// grid 1024 (128 tokens/block), block 256 (4 waves x 32 tokens).
// D[m=channel][n=token]: A = W row-major (c,k), B = x (t,k) from LDS.
// ---------------------------------------------------------------------------
__global__ __launch_bounds__(256, 2) void qk_mfma_kernel(
    const float* __restrict__ x, const unsigned short* __restrict__ whi,
    const unsigned short* __restrict__ wlo, const float* __restrict__ w_g,
    const float* __restrict__ scale, const float* __restrict__ pos_enc,
    float* __restrict__ qout, float* __restrict__ kout,
    float* __restrict__ partial)
{
    __shared__ __align__(16) char smem[65536];   // xhi [0,32K), xlo [32K,64K)
    __shared__ float wpart[4][257];

    const int tid  = threadIdx.x;
    const int w    = tid >> 6;
    const int l    = tid & 63;
    const int blk  = blockIdx.x;
    const int tok0 = blk * 128;                // global token row base
    const int tokb = (blk & 127) * 128;        // token base within batch

    // ---- stage x -> bf16 hi/lo, XOR-swizzled rows ----
#pragma unroll
    for (int it = 0; it < 8; ++it) {
        const int chunk = it * 256 + tid;      // 0..2047
        const int r = chunk >> 4;              // token row 0..127
        const int g = chunk & 15;              // 16B chunk in row
        const float* src = x + (tok0 + r) * 128 + g * 8;
        const float4 a = *(const float4*)(src);
        const float4 b = *(const float4*)(src + 4);
        float f[8] = {a.x, a.y, a.z, a.w, b.x, b.y, b.z, b.w};
        bf16x8 hv, lv;
#pragma unroll
        for (int j = 0; j < 8; ++j) {
            unsigned short h = f2bf(f[j]);
            hv[j] = (short)h;
            lv[j] = (short)f2bf(f[j] - bf2f(h));
        }
        const int ad = r * 256 + ((g * 16) ^ ((r & 7) << 4));
        *(bf16x8*)(smem + ad) = hv;
        *(bf16x8*)(smem + 32768 + ad) = lv;
    }
    __syncthreads();

    // ---- x fragments (B operand) to registers: [n][kt], hi & lo ----
    bf16x8 xh[2][4], xl[2][4];
    {
        const int lg16 = (l >> 4) * 16;
#pragma unroll
        for (int n = 0; n < 2; ++n) {
            const int r = w * 32 + n * 16 + (l & 15);
            const int rb = r * 256;
            const int sw = (r & 7) << 4;
#pragma unroll
            for (int kt = 0; kt < 4; ++kt) {
                const int ad = rb + ((kt * 64 + lg16) ^ sw);
                xh[n][kt] = *(bf16x8*)(smem + ad);
                xl[n][kt] = *(bf16x8*)(smem + 32768 + ad);
            }
        }
    }

    const int crow = (l >> 4) * 4;             // channel sub-offset from C-layout

    f32x4 acc[8][2];
    const unsigned short* wq_hi = whi;
    const unsigned short* wq_lo = wlo;
    const unsigned short* wk_hi = whi + 16384;
    const unsigned short* wk_lo = wlo + 16384;

    // =================== q pass ===================
#pragma unroll
    for (int m = 0; m < 8; ++m)
#pragma unroll
        for (int n = 0; n < 2; ++n) acc[m][n] = (f32x4)0.f;

#pragma unroll
    for (int m = 0; m < 8; ++m) {
        const int c = m * 16 + (l & 15);
        bf16x8 ah[4], al[4];
#pragma unroll
        for (int kt = 0; kt < 4; ++kt) {
            const int off = c * 128 + kt * 32 + (l >> 4) * 8;
            ah[kt] = *(const bf16x8*)(wq_hi + off);
            al[kt] = *(const bf16x8*)(wq_lo + off);
        }
#pragma unroll
        for (int n = 0; n < 2; ++n)
#pragma unroll
            for (int kt = 0; kt < 4; ++kt) {
                acc[m][n] = __builtin_amdgcn_mfma_f32_16x16x32_bf16(ah[kt], xh[n][kt], acc[m][n], 0, 0, 0);
                acc[m][n] = __builtin_amdgcn_mfma_f32_16x16x32_bf16(ah[kt], xl[n][kt], acc[m][n], 0, 0, 0);
                acc[m][n] = __builtin_amdgcn_mfma_f32_16x16x32_bf16(al[kt], xh[n][kt], acc[m][n], 0, 0, 0);
            }
    }

    // ---- q epilogue ----
    {
        // qv = (relu+1e-6)/softplus(scale)
#pragma unroll
        for (int m = 0; m < 8; ++m) {
            const float4 sc = *(const float4*)(scale + m * 16 + crow);
            float is[4] = {1.f / log1pf(expf(sc.x)), 1.f / log1pf(expf(sc.y)),
                           1.f / log1pf(expf(sc.z)), 1.f / log1pf(expf(sc.w))};
#pragma unroll
            for (int n = 0; n < 2; ++n)
#pragma unroll
                for (int j = 0; j < 4; ++j) {
                    float v = fmaxf(acc[m][n][j], 0.f) + 1e-6f;
                    acc[m][n][j] = v * is[j];
                }
        }
        // per-token focusing factor
        float fqn[2];
#pragma unroll
        for (int n = 0; n < 2; ++n) {
            float s2 = 0.f, s6 = 0.f;
#pragma unroll
            for (int m = 0; m < 8; ++m)
#pragma unroll
                for (int j = 0; j < 4; ++j) {
                    const float v = acc[m][n][j];
                    const float v2 = v * v;
                    s2 += v2; s6 += v2 * v2 * v2;
                }
            s2 += __shfl_xor(s2, 16); s6 += __shfl_xor(s6, 16);
            s2 += __shfl_xor(s2, 32); s6 += __shfl_xor(s6, 32);
            fqn[n] = sqrtf(s2 / s6);
        }
#pragma unroll
        for (int m = 0; m < 8; ++m)
#pragma unroll
            for (int n = 0; n < 2; ++n)
#pragma unroll
                for (int j = 0; j < 4; ++j) {
                    const float v = acc[m][n][j];
                    acc[m][n][j] = v * v * v * fqn[n];
                }
        // A_pre
        float d0 = 0.f, d1 = 0.f;
#pragma unroll
        for (int m = 0; m < 8; ++m) {
            const float4 wgv = *(const float4*)(w_g + m * 16 + crow);
            const float wg[4] = {wgv.x, wgv.y, wgv.z, wgv.w};
#pragma unroll
            for (int j = 0; j < 4; ++j) {
                d0 += acc[m][0][j] * wg[j];
                d1 += acc[m][1][j] * wg[j];
            }
        }
        d0 += __shfl_xor(d0, 16); d0 += __shfl_xor(d0, 32);
        d1 += __shfl_xor(d1, 16); d1 += __shfl_xor(d1, 32);
        const float ap0 = 0.25f * d0, ap1 = 0.25f * d1;

        float ssa = ap0 * ap0 + ap1 * ap1;
        ssa += __shfl_xor(ssa, 1); ssa += __shfl_xor(ssa, 2);
        ssa += __shfl_xor(ssa, 4); ssa += __shfl_xor(ssa, 8);
        if (l == 0) wpart[w][256] = ssa;

        // G partial per channel
#pragma unroll
        for (int m = 0; m < 8; ++m) {
            float g[4];
#pragma unroll
            for (int j = 0; j < 4; ++j)
                g[j] = ap0 * acc[m][0][j] + ap1 * acc[m][1][j];
#pragma unroll
            for (int o = 1; o < 16; o <<= 1)
#pragma unroll
                for (int j = 0; j < 4; ++j) g[j] += __shfl_xor(g[j], o);
            if ((l & 15) == 0) {
                const int cb = m * 16 + crow;
                wpart[w][cb] = g[0]; wpart[w][cb + 1] = g[1];
                wpart[w][cb + 2] = g[2]; wpart[w][cb + 3] = g[3];
            }
        }
        // transpose via wave-own LDS, coalesced store
#pragma unroll
        for (int n = 0; n < 2; ++n) {
            const int t = n * 16 + (l & 15);
            const int rb = w * 8192 + (t & 15) * 512 + ((t >= 16) ? 32768 : 0);
#pragma unroll
            for (int m = 0; m < 8; ++m) {
                const int ad = rb + (((m * 16 + crow) * 4) ^ ((t & 7) << 4));
                *(f32x4*)(smem + ad) = acc[m][n];
            }
        }
        asm volatile("s_waitcnt lgkmcnt(0)" ::: "memory");
#pragma unroll
        for (int j = 0; j < 16; ++j) {
            const int fid = j * 64 + l;
            const int row = fid >> 5;
            const int c4 = fid & 31;
            const int rb = w * 8192 + (row & 15) * 512 + ((row >= 16) ? 32768 : 0);
            const f32x4 v = *(f32x4*)(smem + rb + ((c4 * 16) ^ ((row & 7) << 4)));
            *(f32x4*)(qout + (tok0 + w * 32 + row) * 128 + c4 * 4) = v;
        }
    }

    // =================== k pass ===================
#pragma unroll
    for (int m = 0; m < 8; ++m)
#pragma unroll
        for (int n = 0; n < 2; ++n) acc[m][n] = (f32x4)0.f;

#pragma unroll
    for (int m = 0; m < 8; ++m) {
        const int c = m * 16 + (l & 15);
        bf16x8 ah[4], al[4];
#pragma unroll
        for (int kt = 0; kt < 4; ++kt) {
            const int off = c * 128 + kt * 32 + (l >> 4) * 8;
            ah[kt] = *(const bf16x8*)(wk_hi + off);
            al[kt] = *(const bf16x8*)(wk_lo + off);
        }
#pragma unroll
        for (int n = 0; n < 2; ++n)
#pragma unroll
            for (int kt = 0; kt < 4; ++kt) {
                acc[m][n] = __builtin_amdgcn_mfma_f32_16x16x32_bf16(ah[kt], xh[n][kt], acc[m][n], 0, 0, 0);
                acc[m][n] = __builtin_amdgcn_mfma_f32_16x16x32_bf16(ah[kt], xl[n][kt], acc[m][n], 0, 0, 0);
                acc[m][n] = __builtin_amdgcn_mfma_f32_16x16x32_bf16(al[kt], xh[n][kt], acc[m][n], 0, 0, 0);
            }
    }

    // ---- k epilogue ----
    {
#pragma unroll
        for (int m = 0; m < 8; ++m) {
            const float4 sc = *(const float4*)(scale + m * 16 + crow);
            float is[4] = {1.f / log1pf(expf(sc.x)), 1.f / log1pf(expf(sc.y)),
                           1.f / log1pf(expf(sc.z)), 1.f / log1pf(expf(sc.w))};
#pragma unroll
            for (int n = 0; n < 2; ++n) {
                const int t = tokb + w * 32 + n * 16 + (l & 15);
                const float4 p = *(const float4*)(pos_enc + t * 128 + m * 16 + crow);
                const float pe[4] = {p.x, p.y, p.z, p.w};
#pragma unroll
                for (int j = 0; j < 4; ++j) {
                    float v = fmaxf(acc[m][n][j] + pe[j], 0.f) + 1e-6f;
                    acc[m][n][j] = v * is[j];
                }
            }
        }
        float fkn[2];
#pragma unroll
        for (int n = 0; n < 2; ++n) {
            float s2 = 0.f, s6 = 0.f;
#pragma unroll
            for (int m = 0; m < 8; ++m)
#pragma unroll
                for (int j = 0; j < 4; ++j) {
                    const float v = acc[m][n][j];
                    const float v2 = v * v;
                    s2 += v2; s6 += v2 * v2 * v2;
                }
            s2 += __shfl_xor(s2, 16); s6 += __shfl_xor(s6, 16);
            s2 += __shfl_xor(s2, 32); s6 += __shfl_xor(s6, 32);
            fkn[n] = sqrtf(s2 / s6);
        }
#pragma unroll
        for (int m = 0; m < 8; ++m)
#pragma unroll
            for (int n = 0; n < 2; ++n)
#pragma unroll
                for (int j = 0; j < 4; ++j) {
                    const float v = acc[m][n][j];
                    acc[m][n][j] = v * v * v * fkn[n];
                }
        // ksum partial
#pragma unroll
        for (int m = 0; m < 8; ++m) {
            float g[4];
#pragma unroll
            for (int j = 0; j < 4; ++j)
                g[j] = acc[m][0][j] + acc[m][1][j];
#pragma unroll
            for (int o = 1; o < 16; o <<= 1)
#pragma unroll
                for (int j = 0; j < 4; ++j) g[j] += __shfl_xor(g[j], o);
            if ((l & 15) == 0) {
                const int cb = m * 16 + crow;
                wpart[w][128 + cb] = g[0]; wpart[w][128 + cb + 1] = g[1];
                wpart[w][128 + cb + 2] = g[2]; wpart[w][128 + cb + 3] = g[3];
            }
        }
        // transpose + store k
#pragma unroll
        for (int n = 0; n < 2; ++n) {
            const int t = n * 16 + (l & 15);
            const int rb = w * 8192 + (t & 15) * 512 + ((t >= 16) ? 32768 : 0);
#pragma unroll
            for (int m = 0; m < 8; ++m) {
                const int ad = rb + (((m * 16 + crow) * 4) ^ ((t & 7) << 4));
                *(f32x4*)(smem + ad) = acc[m][n];
            }
        }
        asm volatile("s_waitcnt lgkmcnt(0)" ::: "memory");
#pragma unroll
        for (int j = 0; j < 16; ++j) {
            const int fid = j * 64 + l;
            const int row = fid >> 5;
            const int c4 = fid & 31;
            const int rb = w * 8192 + (row & 15) * 512 + ((row >= 16) ? 32768 : 0);
            const f32x4 v = *(f32x4*)(smem + rb + ((c4 * 16) ^ ((row & 7) << 4)));
            *(f32x4*)(kout + (tok0 + w * 32 + row) * 128 + c4 * 4) = v;
        }
    }

    __syncthreads();
    float* pblk = partial + blk * 257;
    if (tid < 128) {
        pblk[tid] = wpart[0][tid] + wpart[1][tid] + wpart[2][tid] + wpart[3][tid];
        pblk[128 + tid] = wpart[0][128 + tid] + wpart[1][128 + tid] +
                          wpart[2][128 + tid] + wpart[3][128 + tid];
    } else if (tid == 128) {
        pblk[256] = wpart[0][256] + wpart[1][256] + wpart[2][256] + wpart[3][256];
    }
}

// ---------------------------------------------------------------------------
// reduce partials -> G, kbar. grid 8, block 256. 128 blocks/batch now.
// ---------------------------------------------------------------------------
__global__ __launch_bounds__(256) void reduce_kernel(
    const float* __restrict__ partial, float* __restrict__ G,
    float* __restrict__ kbar)
{
    const int b = blockIdx.x;
    const int tid = threadIdx.x;
    __shared__ float tmp[4];

    float ssa = (tid < 128) ? partial[(b * 128 + tid) * 257 + 256] : 0.f;
#pragma unroll
    for (int o = 32; o >= 1; o >>= 1) ssa += __shfl_xor(ssa, o);
    if ((tid & 63) == 0) tmp[tid >> 6] = ssa;
    __syncthreads();
    const float anorm = fmaxf(sqrtf(tmp[0] + tmp[1] + tmp[2] + tmp[3]), 1e-12f);
    const float inv_a = 1.f / anorm;

    if (tid < 128) {
        float g = 0.f;
        for (int t = 0; t < 128; ++t)
            g += partial[(b * 128 + t) * 257 + tid];
        G[b * 128 + tid] = g * inv_a;
    } else {
        const int c2 = tid - 128;
        float s = 0.f;
        for (int t = 0; t < 128; ++t)
            s += partial[(b * 128 + t) * 257 + 128 + c2];
        kbar[b * 128 + c2] = s * (1.f / 16384.f);
    }
}

// ---------------------------------------------------------------------------
// scramble: z + gating + cube-transpose. grid 2048, block 256.
// ---------------------------------------------------------------------------
__global__ __launch_bounds__(256) void scramble_kernel(
    const float* __restrict__ q, const float* __restrict__ k,
    const float* __restrict__ G, const float* __restrict__ kbar,
    float* __restrict__ out)
{
    __shared__ float u[64 * 129];
    const int tid  = threadIdx.x;
    const int bid  = blockIdx.x;
    const int half = bid & 1;
    const int r    = (bid >> 1) & 127;
    const int b    = bid >> 8;

    const int t  = tid >> 2;
    const int qt = tid & 3;
    const int tok   = r * 128 + half * 64 + t;
    const int gbase = (b * NN + tok) * CC + qt * 32;
    const int cb    = b * CC + qt * 32;

    float4 qv[8], kv[8], kb4[8], g4[8];
#pragma unroll
    for (int j = 0; j < 8; ++j) {
        qv[j]  = *(const float4*)(q + gbase + j * 4);
        kv[j]  = *(const float4*)(k + gbase + j * 4);
        kb4[j] = *(const float4*)(kbar + cb + j * 4);
        g4[j]  = *(const float4*)(G + cb + j * 4);
    }
    float dot0 = 0.f, dot1 = 0.f;
#pragma unroll
    for (int j = 0; j < 4; ++j) {
        dot0 += qv[j].x * kb4[j].x + qv[j].y * kb4[j].y +
                qv[j].z * kb4[j].z + qv[j].w * kb4[j].w;
        dot1 += qv[j + 4].x * kb4[j + 4].x + qv[j + 4].y * kb4[j + 4].y +
                qv[j + 4].z * kb4[j + 4].z + qv[j + 4].w * kb4[j + 4].w;
    }
    const float z0 = 1.f / (dot0 + 1e-6f);
    const float z1 = 1.f / (dot1 + 1e-6f);

    float* ut = u + t * 129 + qt * 32;
#pragma unroll
    for (int j = 0; j < 8; ++j) {
        const float zz = (j < 4) ? z0 : z1;
        ut[j * 4 + 0] = g4[j].x * kv[j].x * zz;
        ut[j * 4 + 1] = g4[j].y * kv[j].y * zz;
        ut[j * 4 + 2] = g4[j].z * kv[j].z * zz;
        ut[j * 4 + 3] = g4[j].w * kv[j].w * zz;
    }
    __syncthreads();

    const int obase = b * NN * CC + half * 64;
#pragma unroll
    for (int it = 0; it < 32; ++it) {
        const int idx = tid + it * 256;
        const int cc  = idx >> 6;
        const int ch  = idx & 63;
        out[obase + (cc * 128 + r) * CC + ch] = u[ch * 129 + cc];
    }
}

// ---------------------------------------------------------------------------
// depthwise 5x5 conv, RMW into out. grid 4096, block 256.
// ---------------------------------------------------------------------------
__global__ __launch_bounds__(256) void conv_kernel(
    const float* __restrict__ k, const float* __restrict__ dwc_w,
    const float* __restrict__ dwc_b, float* __restrict__ out)
{
    const int tid = threadIdx.x;
    const int l   = tid & 63;
    const int xl  = tid >> 6;
    const int bid = blockIdx.x;
    const int ystrip = bid & 15;
    const int xg  = (bid >> 4) & 31;
    const int b   = bid >> 9;
    const int x   = xg * 4 + xl;
    const int y0  = ystrip * 8;

    const int d0 = (2 * l) & 15;
    const int d1 = (2 * l + 1) & 15;

    float2 w2[25];
#pragma unroll
    for (int j = 0; j < 25; ++j) {
        w2[j].x = dwc_w[d0 * 25 + j];
        w2[j].y = dwc_w[d1 * 25 + j];
    }
    const float bx = dwc_b[d0], by = dwc_b[d1];

    float2 acc[8];
#pragma unroll
    for (int i = 0; i < 8; ++i) acc[i] = make_float2(0.f, 0.f);

    const float2* k2 = (const float2*)k;
    const int base = b * (NN * 64);

    bool mx[5];
#pragma unroll
    for (int dx = 0; dx < 5; ++dx) {
        const int xx = x + dx - 2;
        mx[dx] = (xx >= 0 && xx < 128);
    }

#pragma unroll
    for (int i = 0; i < 12; ++i) {
        const int yy = y0 + i - 2;
        const bool vy = (yy >= 0 && yy < 128);
        float2 c[5];
#pragma unroll
        for (int dx = 0; dx < 5; ++dx) {
            const int xx = x + dx - 2;
            c[dx] = (vy && mx[dx]) ? k2[base + (yy * 128 + xx) * 64 + l]
                                   : make_float2(0.f, 0.f);
        }
#pragma unroll
        for (int dy = 0; dy < 5; ++dy) {
            const int oy = i - dy;
            if (oy < 0 || oy >= 8) continue;
#pragma unroll
            for (int dx = 0; dx < 5; ++dx) {
                acc[oy].x += w2[dy * 5 + dx].x * c[dx].x;
                acc[oy].y += w2[dy * 5 + dx].y * c[dx].y;
            }
        }
    }

    float2* o2 = (float2*)out;
#pragma unroll
    for (int i = 0; i < 8; ++i) {
        const int idx = base + ((y0 + i) * 128 + x) * 64 + l;
        float2 v = o2[idx];
        v.x += acc[i].x + bx;
        v.y += acc[i].y + by;
        o2[idx] = v;
    }
}

// ---------------------------------------------------------------------------
// proj MFMA: out = out @ Wproj.T + bproj (in-place). grid 1024, block 256.
// ---------------------------------------------------------------------------
__global__ __launch_bounds__(256, 2) void proj_mfma_kernel(
    float* __restrict__ out, const unsigned short* __restrict__ whi,
    const unsigned short* __restrict__ wlo, const float* __restrict__ bp)
{
    __shared__ __align__(16) char smem[65536];
    const int tid  = threadIdx.x;
    const int w    = tid >> 6;
    const int l    = tid & 63;
    const int tok0 = blockIdx.x * 128;

#pragma unroll
    for (int it = 0; it < 8; ++it) {
        const int chunk = it * 256 + tid;
        const int r = chunk >> 4;
        const int g = chunk & 15;
        const float* src = out + (tok0 + r) * 128 + g * 8;
        const float4 a = *(const float4*)(src);
        const float4 b = *(const float4*)(src + 4);
        float f[8] = {a.x, a.y, a.z, a.w, b.x, b.y, b.z, b.w};
        bf16x8 hv, lv;
#pragma unroll
        for (int j = 0; j < 8; ++j) {
            unsigned short h = f2bf(f[j]);
            hv[j] = (short)h;
            lv[j] = (short)f2bf(f[j] - bf2f(h));
        }
        const int ad = r * 256 + ((g * 16) ^ ((r & 7) << 4));
        *(bf16x8*)(smem + ad) = hv;
        *(bf16x8*)(smem + 32768 + ad) = lv;
    }
    __syncthreads();

    bf16x8 xh[2][4], xl[2][4];
    {
        const int lg16 = (l >> 4) * 16;
#pragma unroll
        for (int n = 0; n < 2; ++n) {
            const int r = w * 32 + n * 16 + (l & 15);
            const int rb = r * 256;
            const int sw = (r & 7) << 4;
#pragma unroll
            for (int kt = 0; kt < 4; ++kt) {
                const int ad = rb + ((kt * 64 + lg16) ^ sw);
                xh[n][kt] = *(bf16x8*)(smem + ad);
                xl[n][kt] = *(bf16x8*)(smem + 32768 + ad);
            }
        }
    }

    const int crow = (l >> 4) * 4;
    const unsigned short* wp_hi = whi + 32768;
    const unsigned short* wp_lo = wlo + 32768;

    f32x4 acc[8][2];
#pragma unroll
    for (int m = 0; m < 8; ++m)
#pragma unroll
        for (int n = 0; n < 2; ++n) acc[m][n] = (f32x4)0.f;

#pragma unroll
    for (int m = 0; m < 8; ++m) {
        const int c = m * 16 + (l & 15);
        bf16x8 ah[4], al[4];
#pragma unroll
        for (int kt = 0; kt < 4; ++kt) {
            const int off = c * 128 + kt * 32 + (l >> 4) * 8;
            ah[kt] = *(const bf16x8*)(wp_hi + off);
            al[kt] = *(const bf16x8*)(wp_lo + off);
        }
#pragma unroll
        for (int n = 0; n < 2; ++n)
#pragma unroll
            for (int kt = 0; kt < 4; ++kt) {
                acc[m][n] = __builtin_amdgcn_mfma_f32_16x16x32_bf16(ah[kt], xh[n][kt], acc[m][n], 0, 0, 0);
                acc[m][n] = __builtin_amdgcn_mfma_f32_16x16x32_bf16(ah[kt], xl[n][kt], acc[m][n], 0, 0, 0);
                acc[m][n] = __builtin_amdgcn_mfma_f32_16x16x32_bf16(al[kt], xh[n][kt], acc[m][n], 0, 0, 0);
            }
    }

    // bias + transpose + store
#pragma unroll
    for (int m = 0; m < 8; ++m) {
        const float4 bv = *(const float4*)(bp + m * 16 + crow);
        const float bb[4] = {bv.x, bv.y, bv.z, bv.w};
#pragma unroll
        for (int n = 0; n < 2; ++n)
#pragma unroll
            for (int j = 0; j < 4; ++j) acc[m][n][j] += bb[j];
    }
    __syncthreads();   // ensure all waves done reading staged x before overwrite
#pragma unroll
    for (int n = 0; n < 2; ++n) {
        const int t = n * 16 + (l & 15);
        const int rb = w * 8192 + (t & 15) * 512 + ((t >= 16) ? 32768 : 0);
#pragma unroll
        for (int m = 0; m < 8; ++m) {
            const int ad = rb + (((m * 16 + crow) * 4) ^ ((t & 7) << 4));
            *(f32x4*)(smem + ad) = acc[m][n];
        }
    }
    asm volatile("s_waitcnt lgkmcnt(0)" ::: "memory");
#pragma unroll
    for (int j = 0; j < 16; ++j) {
        const int fid = j * 64 + l;
        const int row = fid >> 5;
        const int c4 = fid & 31;
        const int rb = w * 8192 + (row & 15) * 512 + ((row >= 16) ? 32768 : 0);
        const f32x4 v = *(f32x4*)(smem + rb + ((c4 * 16) ^ ((row & 7) << 4)));
        *(f32x4*)(out + (tok0 + w * 32 + row) * 128 + c4 * 4) = v;
    }
}

// ---------------------------------------------------------------------------
extern "C" void kernel_launch(void* const* d_in, const int* in_sizes, int n_in,
                              void* d_out, int out_size, void* d_ws, size_t ws_size,
                              hipStream_t stream)
{
    const float* x       = (const float*)d_in[0];
    const float* Wq      = (const float*)d_in[1];
    const float* Wkv     = (const float*)d_in[2];
    const float* Wproj   = (const float*)d_in[3];
    const float* bproj   = (const float*)d_in[4];
    const float* w_g     = (const float*)d_in[5];
    const float* scale   = (const float*)d_in[6];
    const float* pos_enc = (const float*)d_in[7];
    const float* dwc_w   = (const float*)d_in[8];
    const float* dwc_b   = (const float*)d_in[9];
    float* out = (float*)d_out;

    char* ws = (char*)d_ws;
    float* qbuf    = (float*)(ws);                        // 67108864 B
    float* kbuf    = (float*)(ws + 67108864);             // 67108864 B
    float* partial = (float*)(ws + 134217728);            // 1024*257*4 = 1052672 B
    float* G       = (float*)(ws + 135270400);            // 4096 B
    float* kbar    = (float*)(ws + 135274496);            // 4096 B
    unsigned short* whi = (unsigned short*)(ws + 135278592);  // 98304 B
    unsigned short* wlo = (unsigned short*)(ws + 135376896);  // 98304 B

    wprep_kernel<<<dim3(48), dim3(256), 0, stream>>>(Wq, Wkv, Wproj, whi, wlo);
    qk_mfma_kernel<<<dim3(1024), dim3(256), 0, stream>>>(
        x, whi, wlo, w_g, scale, pos_enc, qbuf, kbuf, partial);
    reduce_kernel<<<dim3(8), dim3(256), 0, stream>>>(partial, G, kbar);
    scramble_kernel<<<dim3(2048), dim3(256), 0, stream>>>(
        qbuf, kbuf, G, kbar, out);
    conv_kernel<<<dim3(4096), dim3(256), 0, stream>>>(
        kbuf, dwc_w, dwc_b, out);
    proj_mfma_kernel<<<dim3(1024), dim3(256), 0, stream>>>(
        out, whi, wlo, bproj);
}